// Round 6
// baseline (300.583 us; speedup 1.0000x reference)
//
#include <hip/hip_runtime.h>

#define T_STEPS 200
#define OUTD 28

typedef float f2 __attribute__((ext_vector_type(2)));

// Gate rows are pre-scaled at load time: i,f,o rows by -log2(e) so
// sigmoid(x) = rcp(1 + exp2(y)) with y = -1.4427*x already folded into the
// dot product; g row by +2*log2(e) so tanh(x) = 1 - 2*rcp(1 + exp2(y)).
__device__ __forceinline__ float sg(float y) {          // sigmoid, pre-scaled input
    return __builtin_amdgcn_rcpf(1.0f + __builtin_amdgcn_exp2f(y));
}
__device__ __forceinline__ float tg(float y) {          // tanh, pre-scaled input
    return 1.0f - 2.0f * __builtin_amdgcn_rcpf(1.0f + __builtin_amdgcn_exp2f(y));
}
__device__ __forceinline__ float tanhc(float x) {       // tanh, raw input (cell)
    return 1.0f - 2.0f * __builtin_amdgcn_rcpf(1.0f + __builtin_amdgcn_exp2f(2.8853900817779268f * x));
}

// Broadcast lane SRC of each quad to all 4 lanes of the quad (one VALU op).
template<int SRC>
__device__ __forceinline__ float qb(float v) {
    return __int_as_float(__builtin_amdgcn_update_dpp(
        0, __float_as_int(v), SRC * 0x55, 0xF, 0xF, true));
}

// Pin values into VGPRs: asm output is opaque -> cannot be rematerialized.
#define PIN2(v) asm volatile("" : "+v"(v))
#define PINF(v) asm volatile("" : "+v"(v))

// Prep: Wt[t][j][c] = Wout[j][4t+c]  (per-step Wout column contiguous:
// uniform base bump 448B/step + constant lane offset).
__global__ void transpose_wout(const float* __restrict__ Wout, float* __restrict__ Wt) {
    int idx = blockIdx.x * 256 + threadIdx.x;     // 200*28*4 = 22400
    if (idx < T_STEPS * OUTD * 4) {
        int t = idx / (OUTD * 4);
        int r = idx - t * (OUTD * 4);
        int j = r >> 2, c = r & 3;
        Wt[idx] = Wout[j * 800 + 4 * t + c];
    }
}

// 4 lanes per batch element (lane k owns hidden unit k: gate rows
// k,4+k,8+k,12+k of both layers). 32768*4 = 131072 threads = 2048 waves =
// 2 waves/SIMD on all 1024 SIMDs -> TLP fills trans/VMEM gaps. Per-wave
// live set ~157 regs fits the 2-wave 256-reg budget; waves_per_eu(2,2)
// pins the allocator to that budget and asm pins stop weight
// rematerialization (R5: pins+waves_per_eu honest VGPR=132; R4 without
// pins collapsed to 88 with per-step reloads).
__global__ __launch_bounds__(256)
__attribute__((amdgpu_waves_per_eu(2, 2)))
void lstm2_fused(const float* __restrict__ x,
                 const float* __restrict__ Wih0, const float* __restrict__ Whh0,
                 const float* __restrict__ bih0, const float* __restrict__ bhh0,
                 const float* __restrict__ Wih1, const float* __restrict__ Whh1,
                 const float* __restrict__ bih1, const float* __restrict__ bhh1,
                 const float* __restrict__ Wt,   const float* __restrict__ bout,
                 float* __restrict__ out, int batch)
{
    const int tid = blockIdx.x * 256 + threadIdx.x;
    const int b = tid >> 2;       // batch element
    const int k = tid & 3;        // hidden unit owned by this lane
    if (b >= batch) return;       // never taken

    // ---- per-lane weights into registers (f2 pairs), gate-pre-scaled ----
    f2 wi0a[4], wi0b[4], wh0a[4], wh0b[4];
    f2 wi1a[4], wi1b[4], wh1a[4], wh1b[4];
    float b0[4], b1[4];
#pragma unroll
    for (int gi = 0; gi < 4; ++gi) {
        const int row = gi * 4 + k;              // rows k,4+k,8+k,12+k
        // i,f,o rows: *-log2e (sigmoid); g row (gi==2): *2*log2e (tanh)
        const float sc = (gi == 2) ? 2.8853900817779268f : -1.4426950408889634f;
        float4 a = ((const float4*)Wih0)[row];
        float4 c = ((const float4*)Whh0)[row];
        float4 d = ((const float4*)Wih1)[row];
        float4 e = ((const float4*)Whh1)[row];
        wi0a[gi] = f2{a.x * sc, a.y * sc}; wi0b[gi] = f2{a.z * sc, a.w * sc};
        wh0a[gi] = f2{c.x * sc, c.y * sc}; wh0b[gi] = f2{c.z * sc, c.w * sc};
        wi1a[gi] = f2{d.x * sc, d.y * sc}; wi1b[gi] = f2{d.z * sc, d.w * sc};
        wh1a[gi] = f2{e.x * sc, e.y * sc}; wh1b[gi] = f2{e.z * sc, e.w * sc};
        b0[gi] = (bih0[row] + bhh0[row]) * sc;
        b1[gi] = (bih1[row] + bhh1[row]) * sc;
    }
#pragma unroll
    for (int gi = 0; gi < 4; ++gi) {
        PIN2(wi0a[gi]); PIN2(wi0b[gi]); PIN2(wh0a[gi]); PIN2(wh0b[gi]);
        PIN2(wi1a[gi]); PIN2(wi1b[gi]); PIN2(wh1a[gi]); PIN2(wh1b[gi]);
        PINF(b0[gi]);   PINF(b1[gi]);
    }

    f2 acc[7];
#pragma unroll
    for (int jj = 0; jj < 7; ++jj) acc[jj] = f2{bout[k * 7 + jj], 0.0f};

    f2 h1a = f2{0,0}, h1b = f2{0,0}, h2a = f2{0,0}, h2b = f2{0,0};
    float c1 = 0.0f, c2 = 0.0f;

    // Uniform bases (SALU-advanced) + constant per-lane byte offsets.
    const char* xp  = (const char*)x;
    const unsigned x_off = (unsigned)b * 3200u;       // b * 200*4*4B
    const char* wtp = (const char*)Wt;                // + 448 each step
    const unsigned w_off = (unsigned)k * 112u;        // k*7 rows * 16B

    // Depth-2 x prefetch.
    float4 xv = *(const float4*)(xp + x_off);
    float4 xn = *(const float4*)(xp + x_off + 16);

    for (int t = 0; t < T_STEPS; ++t) {
        // ---- this step's Wout column + x two steps ahead, issued early ----
        float4 wo[7];
#pragma unroll
        for (int jj = 0; jj < 7; ++jj)
            wo[jj] = *(const float4*)(wtp + w_off + jj * 16);
        wtp += OUTD * 16;                              // uniform s_add

        int tn = t + 2; if (tn >= T_STEPS) tn = T_STEPS - 1;   // uniform
        float4 xf = *(const float4*)(xp + x_off + (size_t)tn * 16);

        f2 xa = f2{xv.x, xv.y}, xb = f2{xv.z, xv.w};

        // ---- layer 1: 4 pre-scaled gate rows for unit k ----
        float g[4];
#pragma unroll
        for (int gi = 0; gi < 4; ++gi) {
            f2 s = wi0a[gi] * xa;
            s += wi0b[gi] * xb;
            s += wh0a[gi] * h1a;
            s += wh0b[gi] * h1b;
            g[gi] = b0[gi] + s.x + s.y;
        }
        {
            float ig = sg(g[0]), fg = sg(g[1]);
            float gg = tg(g[2]), og = sg(g[3]);
            c1 = fg * c1 + ig * gg;
            float ho = og * tanhc(c1);
            h1a = f2{qb<0>(ho), qb<1>(ho)};
            h1b = f2{qb<2>(ho), qb<3>(ho)};
        }

        // ---- layer 2 ----
#pragma unroll
        for (int gi = 0; gi < 4; ++gi) {
            f2 s = wi1a[gi] * h1a;
            s += wi1b[gi] * h1b;
            s += wh1a[gi] * h2a;
            s += wh1b[gi] * h2b;
            g[gi] = b1[gi] + s.x + s.y;
        }
        {
            float ig = sg(g[0]), fg = sg(g[1]);
            float gg = tg(g[2]), og = sg(g[3]);
            c2 = fg * c2 + ig * gg;
            float ho = og * tanhc(c2);
            h2a = f2{qb<0>(ho), qb<1>(ho)};
            h2b = f2{qb<2>(ho), qb<3>(ho)};
        }

        // ---- fused linear: this lane's 7 outputs (packed accumulators) ----
#pragma unroll
        for (int jj = 0; jj < 7; ++jj) {
            acc[jj] += f2{wo[jj].x, wo[jj].y} * h2a;
            acc[jj] += f2{wo[jj].z, wo[jj].w} * h2b;
        }

        xv = xn;
        xn = xf;
    }

    float* op = out + (size_t)b * OUTD + k * 7;
#pragma unroll
    for (int jj = 0; jj < 7; ++jj) op[jj] = acc[jj].x + acc[jj].y;
}

extern "C" void kernel_launch(void* const* d_in, const int* in_sizes, int n_in,
                              void* d_out, int out_size, void* d_ws, size_t ws_size,
                              hipStream_t stream) {
    const float* x    = (const float*)d_in[0];
    const float* Wih0 = (const float*)d_in[1];
    const float* Whh0 = (const float*)d_in[2];
    const float* bih0 = (const float*)d_in[3];
    const float* bhh0 = (const float*)d_in[4];
    const float* Wih1 = (const float*)d_in[5];
    const float* Whh1 = (const float*)d_in[6];
    const float* bih1 = (const float*)d_in[7];
    const float* bhh1 = (const float*)d_in[8];
    const float* Wout = (const float*)d_in[9];
    const float* bout = (const float*)d_in[10];
    float* out = (float*)d_out;
    float* Wt  = (float*)d_ws;      // 200*28*4 floats = 89.6 KB

    transpose_wout<<<(T_STEPS * OUTD * 4 + 255) / 256, 256, 0, stream>>>(Wout, Wt);

    const int batch = in_sizes[0] / (T_STEPS * 4);   // 32768
    const int threads = batch * 4;                   // 131072
    const int grid = threads / 256;                  // 512
    lstm2_fused<<<grid, 256, 0, stream>>>(
        x, Wih0, Whh0, bih0, bhh0, Wih1, Whh1, bih1, bhh1, Wt, bout, out, batch);
}

// Round 7
// 241.932 us; speedup vs baseline: 1.2424x; 1.2424x over previous
//
#include <hip/hip_runtime.h>

#define T_STEPS 200
#define OUTD 28

typedef float f2 __attribute__((ext_vector_type(2)));

// Gate rows pre-scaled at weight-load time: i,f,o rows by -log2(e) so
// sigmoid(x) = rcp(1 + exp2(y)); g row by +2*log2(e) so
// tanh(x) = 1 - 2*rcp(1 + exp2(y)). Saves one v_mul per activation and
// shortens the chain into the trans unit.
__device__ __forceinline__ float sg(float y) {          // sigmoid, pre-scaled
    return __builtin_amdgcn_rcpf(1.0f + __builtin_amdgcn_exp2f(y));
}
__device__ __forceinline__ float tg(float y) {          // tanh, pre-scaled
    return 1.0f - 2.0f * __builtin_amdgcn_rcpf(1.0f + __builtin_amdgcn_exp2f(y));
}
__device__ __forceinline__ float tanhc(float x) {       // tanh, raw (cell path)
    return 1.0f - 2.0f * __builtin_amdgcn_rcpf(1.0f + __builtin_amdgcn_exp2f(2.8853900817779268f * x));
}

// Broadcast lane SRC of each quad to all 4 lanes of the quad (one VALU op).
template<int SRC>
__device__ __forceinline__ float qb(float v) {
    return __int_as_float(__builtin_amdgcn_update_dpp(
        0, __float_as_int(v), SRC * 0x55, 0xF, 0xF, true));
}

// Pin values into VGPRs (asm output is opaque -> no rematerialization).
// Only effective in the waves_per_eu(1,1) 512-reg regime (R5 vs R6 finding).
#define PIN2(v) asm volatile("" : "+v"(v))
#define PINF(v) asm volatile("" : "+v"(v))

// Prep: Wt[t][j][c] = Wout[j][4t+c]  (per-step Wout column contiguous:
// uniform base bump 448B/step + constant lane offset).
__global__ void transpose_wout(const float* __restrict__ Wout, float* __restrict__ Wt) {
    int idx = blockIdx.x * 256 + threadIdx.x;     // 200*28*4 = 22400
    if (idx < T_STEPS * OUTD * 4) {
        int t = idx / (OUTD * 4);
        int r = idx - t * (OUTD * 4);
        int j = r >> 2, c = r & 3;
        Wt[idx] = Wout[j * 800 + 4 * t + c];
    }
}

// One layer step for one element; lane k owns unit k. Pre-scaled gates.
__device__ __forceinline__ void layer_step(const f2 (&wia)[4], const f2 (&wib)[4],
                                           const f2 (&wha)[4], const f2 (&whb)[4],
                                           const float (&bb)[4],
                                           f2 ina, f2 inb,
                                           f2& ha, f2& hb, float& c)
{
    float g[4];
#pragma unroll
    for (int gi = 0; gi < 4; ++gi) {
        f2 s = wia[gi] * ina;
        s += wib[gi] * inb;
        s += wha[gi] * ha;
        s += whb[gi] * hb;
        g[gi] = bb[gi] + s.x + s.y;
    }
    float ig = sg(g[0]), fg = sg(g[1]);
    float gg = tg(g[2]), og = sg(g[3]);
    c = fg * c + ig * gg;
    float ho = og * tanhc(c);
    ha = f2{qb<0>(ho), qb<1>(ho)};
    hb = f2{qb<2>(ho), qb<3>(ho)};
}

// One full timestep for both elements of this lane's pair.
// Consumes x from (xs0,xs1) and, if PREF, refills the SAME slots with
// x[tpf] (issued right after layer-1's last read -> zero rotation movs,
// ~1.5 steps of latency cover).
template<bool PREF>
__device__ __forceinline__ void full_step(
    const f2 (&wi0a)[4], const f2 (&wi0b)[4], const f2 (&wh0a)[4], const f2 (&wh0b)[4],
    const f2 (&wi1a)[4], const f2 (&wi1b)[4], const f2 (&wh1a)[4], const f2 (&wh1b)[4],
    const float (&b0)[4], const float (&b1)[4],
    f2& h1a0, f2& h1b0, f2& h2a0, f2& h2b0, float& c10, float& c20,
    f2& h1a1, f2& h1b1, f2& h2a1, f2& h2b1, float& c11, float& c21,
    f2 (&acc0)[7], f2 (&acc1)[7],
    float4& xs0, float4& xs1,
    const char* xp, unsigned xo0, unsigned xo1, int tpf,
    const char* wtp, unsigned w_off)
{
    // This step's Wout column (shared by both elements).
    float4 wo[7];
#pragma unroll
    for (int jj = 0; jj < 7; ++jj)
        wo[jj] = *(const float4*)(wtp + w_off + jj * 16);

    f2 xa0 = f2{xs0.x, xs0.y}, xb0 = f2{xs0.z, xs0.w};
    f2 xa1 = f2{xs1.x, xs1.y}, xb1 = f2{xs1.z, xs1.w};

    // ---- layer 1, both elements (independent chains -> ILP) ----
    layer_step(wi0a, wi0b, wh0a, wh0b, b0, xa0, xb0, h1a0, h1b0, c10);
    layer_step(wi0a, wi0b, wh0a, wh0b, b0, xa1, xb1, h1a1, h1b1, c11);

    // x slots are dead now: refill with x[tpf] (consumed 2 steps later).
    if (PREF) {
        xs0 = *(const float4*)(xp + xo0 + (size_t)tpf * 16);
        xs1 = *(const float4*)(xp + xo1 + (size_t)tpf * 16);
    }

    // ---- layer 2, both elements ----
    layer_step(wi1a, wi1b, wh1a, wh1b, b1, h1a0, h1b0, h2a0, h2b0, c20);
    layer_step(wi1a, wi1b, wh1a, wh1b, b1, h1a1, h1b1, h2a1, h2b1, c21);

    // ---- fused linear, both elements (wo shared) ----
#pragma unroll
    for (int jj = 0; jj < 7; ++jj) {
        f2 wa = f2{wo[jj].x, wo[jj].y};
        f2 wb = f2{wo[jj].z, wo[jj].w};
        acc0[jj] += wa * h2a0; acc0[jj] += wb * h2b0;
        acc1[jj] += wa * h2a1; acc1[jj] += wb * h2b1;
    }
}

// 4 lanes per batch-element PAIR: lane k owns hidden unit k of TWO elements
// (weights shared). 65536 threads = 1024 waves = exactly 1 wave/SIMD;
// waves_per_eu(1,1) gives the allocator the 512-reg budget — the only
// regime where the weight set is honestly register-resident (R5: VGPR=132;
// R4/R6 at 2 waves/SIMD collapsed to 88 with per-step reloads even with
// pins). Latency hiding = in-wave ILP from the two independent chains.
__global__ __launch_bounds__(256)
__attribute__((amdgpu_waves_per_eu(1, 1)))
void lstm2_fused(const float* __restrict__ x,
                 const float* __restrict__ Wih0, const float* __restrict__ Whh0,
                 const float* __restrict__ bih0, const float* __restrict__ bhh0,
                 const float* __restrict__ Wih1, const float* __restrict__ Whh1,
                 const float* __restrict__ bih1, const float* __restrict__ bhh1,
                 const float* __restrict__ Wt,   const float* __restrict__ bout,
                 float* __restrict__ out, int batch)
{
    const int tid = blockIdx.x * 256 + threadIdx.x;
    const int quad = tid >> 2;     // element pair
    const int k = tid & 3;         // hidden unit owned by this lane
    const int e0 = quad * 2, e1 = e0 + 1;
    if (e1 >= batch) return;       // never taken (batch even)

    // ---- per-lane weights into registers (f2 pairs), gate-pre-scaled ----
    f2 wi0a[4], wi0b[4], wh0a[4], wh0b[4];
    f2 wi1a[4], wi1b[4], wh1a[4], wh1b[4];
    float b0[4], b1[4];
#pragma unroll
    for (int gi = 0; gi < 4; ++gi) {
        const int row = gi * 4 + k;              // rows k,4+k,8+k,12+k
        const float sc = (gi == 2) ? 2.8853900817779268f : -1.4426950408889634f;
        float4 a = ((const float4*)Wih0)[row];
        float4 c = ((const float4*)Whh0)[row];
        float4 d = ((const float4*)Wih1)[row];
        float4 e = ((const float4*)Whh1)[row];
        wi0a[gi] = f2{a.x * sc, a.y * sc}; wi0b[gi] = f2{a.z * sc, a.w * sc};
        wh0a[gi] = f2{c.x * sc, c.y * sc}; wh0b[gi] = f2{c.z * sc, c.w * sc};
        wi1a[gi] = f2{d.x * sc, d.y * sc}; wi1b[gi] = f2{d.z * sc, d.w * sc};
        wh1a[gi] = f2{e.x * sc, e.y * sc}; wh1b[gi] = f2{e.z * sc, e.w * sc};
        b0[gi] = (bih0[row] + bhh0[row]) * sc;
        b1[gi] = (bih1[row] + bhh1[row]) * sc;
    }
#pragma unroll
    for (int gi = 0; gi < 4; ++gi) {
        PIN2(wi0a[gi]); PIN2(wi0b[gi]); PIN2(wh0a[gi]); PIN2(wh0b[gi]);
        PIN2(wi1a[gi]); PIN2(wi1b[gi]); PIN2(wh1a[gi]); PIN2(wh1b[gi]);
        PINF(b0[gi]);   PINF(b1[gi]);
    }

    f2 acc0[7], acc1[7];
#pragma unroll
    for (int jj = 0; jj < 7; ++jj) {
        float bj = bout[k * 7 + jj];
        acc0[jj] = f2{bj, 0.0f};
        acc1[jj] = f2{bj, 0.0f};
    }

    f2 h1a0 = f2{0,0}, h1b0 = f2{0,0}, h2a0 = f2{0,0}, h2b0 = f2{0,0};
    f2 h1a1 = f2{0,0}, h1b1 = f2{0,0}, h2a1 = f2{0,0}, h2b1 = f2{0,0};
    float c10 = 0.0f, c20 = 0.0f, c11 = 0.0f, c21 = 0.0f;

    // Uniform bases (SALU-advanced) + constant per-lane byte offsets.
    const char* xp  = (const char*)x;
    const unsigned xo0 = (unsigned)e0 * 3200u;        // e * 200*4*4B
    const unsigned xo1 = (unsigned)e1 * 3200u;
    const char* wtp = (const char*)Wt;                // + 448 each step
    const unsigned w_off = (unsigned)k * 112u;        // k*7 rows * 16B

    // Slot A holds even steps' x, slot B odd steps'.
    float4 xv0 = *(const float4*)(xp + xo0);
    float4 xv1 = *(const float4*)(xp + xo1);
    float4 xn0 = *(const float4*)(xp + xo0 + 16);
    float4 xn1 = *(const float4*)(xp + xo1 + 16);

    // Main loop: unroll x2 with slot-role swap (zero rotation movs).
    for (int t = 0; t < T_STEPS - 2; t += 2) {
        full_step<true>(wi0a, wi0b, wh0a, wh0b, wi1a, wi1b, wh1a, wh1b, b0, b1,
                        h1a0, h1b0, h2a0, h2b0, c10, c20,
                        h1a1, h1b1, h2a1, h2b1, c11, c21,
                        acc0, acc1, xv0, xv1, xp, xo0, xo1, t + 2, wtp, w_off);
        wtp += OUTD * 16;
        full_step<true>(wi0a, wi0b, wh0a, wh0b, wi1a, wi1b, wh1a, wh1b, b0, b1,
                        h1a0, h1b0, h2a0, h2b0, c10, c20,
                        h1a1, h1b1, h2a1, h2b1, c11, c21,
                        acc0, acc1, xn0, xn1, xp, xo0, xo1, t + 3, wtp, w_off);
        wtp += OUTD * 16;
    }
    // Epilogue: steps 198 (slot A) and 199 (slot B), no prefetch.
    full_step<false>(wi0a, wi0b, wh0a, wh0b, wi1a, wi1b, wh1a, wh1b, b0, b1,
                     h1a0, h1b0, h2a0, h2b0, c10, c20,
                     h1a1, h1b1, h2a1, h2b1, c11, c21,
                     acc0, acc1, xv0, xv1, xp, xo0, xo1, 0, wtp, w_off);
    wtp += OUTD * 16;
    full_step<false>(wi0a, wi0b, wh0a, wh0b, wi1a, wi1b, wh1a, wh1b, b0, b1,
                     h1a0, h1b0, h2a0, h2b0, c10, c20,
                     h1a1, h1b1, h2a1, h2b1, c11, c21,
                     acc0, acc1, xn0, xn1, xp, xo0, xo1, 0, wtp, w_off);

    float* op0 = out + (size_t)e0 * OUTD + k * 7;
    float* op1 = out + (size_t)e1 * OUTD + k * 7;
#pragma unroll
    for (int jj = 0; jj < 7; ++jj) {
        op0[jj] = acc0[jj].x + acc0[jj].y;
        op1[jj] = acc1[jj].x + acc1[jj].y;
    }
}

extern "C" void kernel_launch(void* const* d_in, const int* in_sizes, int n_in,
                              void* d_out, int out_size, void* d_ws, size_t ws_size,
                              hipStream_t stream) {
    const float* x    = (const float*)d_in[0];
    const float* Wih0 = (const float*)d_in[1];
    const float* Whh0 = (const float*)d_in[2];
    const float* bih0 = (const float*)d_in[3];
    const float* bhh0 = (const float*)d_in[4];
    const float* Wih1 = (const float*)d_in[5];
    const float* Whh1 = (const float*)d_in[6];
    const float* bih1 = (const float*)d_in[7];
    const float* bhh1 = (const float*)d_in[8];
    const float* Wout = (const float*)d_in[9];
    const float* bout = (const float*)d_in[10];
    float* out = (float*)d_out;
    float* Wt  = (float*)d_ws;      // 200*28*4 floats = 89.6 KB

    transpose_wout<<<(T_STEPS * OUTD * 4 + 255) / 256, 256, 0, stream>>>(Wout, Wt);

    const int batch = in_sizes[0] / (T_STEPS * 4);   // 32768
    const int threads = (batch / 2) * 4;             // 65536
    const int grid = threads / 256;                  // 256
    lstm2_fused<<<grid, 256, 0, stream>>>(
        x, Wih0, Whh0, bih0, bhh0, Wih1, Whh1, bih1, bhh1, Wt, bout, out, batch);
}